// Round 20
// baseline (102.157 us; speedup 1.0000x reference)
//
#include <hip/hip_runtime.h>

// Problem constants (fixed by the reference)
#define N_NODES   100000
#define N_EDGES   1600000
#define IN_CH     16
#define HID_CH    64
#define OUT_CH    128
#define N_GRAPHS  128

// Capacities. Expected: slots ~2.2K, list1 ~35K, list2 ~2K.
#define CAPS  4096
#define CAP1  65536
#define CAP2  16384

#define BM_WORDS ((N_NODES + 31) / 32)      // 3125 words; snapshot 3136, alloc 3200
#define BM_PAD   3200

#define NBLK   512                          // 2 blocks/CU: guaranteed co-resident
#define GROUPS 32
#define GSIZE  (NBLK / GROUPS)              // 16 blocks per barrier leaf
#define SCAN_CHUNK 3128                     // 4-aligned; 512*3128 >= N_EDGES
#define SCAN_V   (SCAN_CHUNK / 4)

// LDS arena (ints).  Scan phases: bm@0(3136) | lbuf@3136(3128) | scnt@6264
// Phase E: w1s@0(1024) | b1s@1024(64) | w2s@1088(8192) | cent@9280(128)
#define SMEM_INTS 9472
#define LBUF_OFF  3136
#define SCNT_OFF  6264

typedef int      iv4 __attribute__((ext_vector_type(4)));
typedef unsigned uv4 __attribute__((ext_vector_type(4)));
typedef float    fv4 __attribute__((ext_vector_type(4)));

// ---- agent-scope scalar accessors (memory-side coherence point) ----
__device__ __forceinline__ int aload(const int* p) {
    return __hip_atomic_load(p, __ATOMIC_RELAXED, __HIP_MEMORY_SCOPE_AGENT);
}
__device__ __forceinline__ unsigned auload(const unsigned* p) {
    return __hip_atomic_load(p, __ATOMIC_RELAXED, __HIP_MEMORY_SCOPE_AGENT);
}
__device__ __forceinline__ float afload(const float* p) {
    return __hip_atomic_load(p, __ATOMIC_RELAXED, __HIP_MEMORY_SCOPE_AGENT);
}
__device__ __forceinline__ void astore(int* p, int v) {
    __hip_atomic_store(p, v, __ATOMIC_RELAXED, __HIP_MEMORY_SCOPE_AGENT);
}

// ---- CP-serviced 16B vector ops (sc0 sc1 = bypass L1+L2) ----
__device__ __forceinline__ void cpstore4u(unsigned* p, uv4 v) {
    asm volatile("global_store_dwordx4 %0, %1, off sc0 sc1" :: "v"(p), "v"(v) : "memory");
}
__device__ __forceinline__ void cpstore4f(float* p, fv4 v) {
    asm volatile("global_store_dwordx4 %0, %1, off sc0 sc1" :: "v"(p), "v"(v) : "memory");
}

// Snapshot padded bitmap (3136 words) global->LDS via CP vec loads.
// "=&v" early-clobber is load-bearing (R14 crash without it).
__device__ __forceinline__ void snap_bm(const unsigned* g, unsigned* lds) {
    int t = threadIdx.x;
    if (t < 196) {
        const unsigned* ptr = g + t * 16;
        uv4 a, b, c, d;
        asm volatile(
            "global_load_dwordx4 %0, %4, off sc0 sc1\n\t"
            "global_load_dwordx4 %1, %4, off offset:16 sc0 sc1\n\t"
            "global_load_dwordx4 %2, %4, off offset:32 sc0 sc1\n\t"
            "global_load_dwordx4 %3, %4, off offset:48 sc0 sc1\n\t"
            "s_waitcnt vmcnt(0)"
            : "=&v"(a), "=&v"(b), "=&v"(c), "=&v"(d)
            : "v"(ptr) : "memory");
        *(uv4*)(lds + t * 16)      = a;
        *(uv4*)(lds + t * 16 + 4)  = b;
        *(uv4*)(lds + t * 16 + 8)  = c;
        *(uv4*)(lds + t * 16 + 12) = d;
    }
    __syncthreads();
}

// ---- tree barrier (monotonic; zeroed by k_prep; R13-validated relaxed form) ----
struct GBar { int leaf[GROUPS * 16]; int root[16]; int rootrel[16]; int leafrel[GROUPS * 16]; };
#define BAR_INTS ((int)(sizeof(GBar) / 4))

struct P {
    const float* x; const int* src; const int* dst; const int* ptr;
    const float* W1; const float* b1; const float* W2; const float* b2;
    float* out;
    unsigned* deg; int* map1; int* slotnode; int* list1; int* list2;
    float* agg1; unsigned* markbm; unsigned* ndbm; int* cnt; GBar* bar;
};

__device__ __forceinline__ void gbar(GBar* b, int k) {
    asm volatile("s_waitcnt vmcnt(0) lgkmcnt(0)" ::: "memory");
    __syncthreads();
    if (threadIdx.x == 0) {
        int g = blockIdx.x / GSIZE;
        int a = __hip_atomic_fetch_add(&b->leaf[g * 16], 1, __ATOMIC_RELAXED,
                                       __HIP_MEMORY_SCOPE_AGENT);
        if (a == GSIZE * k - 1) {
            int r = __hip_atomic_fetch_add(&b->root[0], 1, __ATOMIC_RELAXED,
                                           __HIP_MEMORY_SCOPE_AGENT);
            if (r == GROUPS * k - 1) {
                __hip_atomic_store(&b->rootrel[0], k, __ATOMIC_RELAXED,
                                   __HIP_MEMORY_SCOPE_AGENT);
            } else {
                while (__hip_atomic_load(&b->rootrel[0], __ATOMIC_RELAXED,
                                         __HIP_MEMORY_SCOPE_AGENT) < k)
                    __builtin_amdgcn_s_sleep(2);
            }
            __hip_atomic_store(&b->leafrel[g * 16], k, __ATOMIC_RELAXED,
                               __HIP_MEMORY_SCOPE_AGENT);
        } else {
            while (__hip_atomic_load(&b->leafrel[g * 16], __ATOMIC_RELAXED,
                                     __HIP_MEMORY_SCOPE_AGENT) < k)
                __builtin_amdgcn_s_sleep(2);
        }
    }
    __syncthreads();
}

// ---------------- phases ----------------
// Cross-phase data discipline (coop mode): all mutable cross-phase buffers
// accessed ONLY via global atomics / CP stores / aload (all memory-side).
// Read-only inputs (x, src, dst, ptr, W*, b*) use normal cached loads.

// Phase A: CP-zero deg/agg1, CP-init out=b2; LDS central bitmap from ptr;
// scan: central-dst edges -> list2, srcs (+centrals via block 0) -> markbm.
__device__ void ph_A(const P& p, int* smem) {
    unsigned* cbm = (unsigned*)smem;
    int* lbuf = smem + LBUF_OFF;
    int* scnt = smem + SCNT_OFF;
    for (int t = threadIdx.x; t < 3136; t += blockDim.x) cbm[t] = 0u;
    if (threadIdx.x == 0) scnt[0] = 0;
    __syncthreads();
    if (threadIdx.x < N_GRAPHS) {
        int c = p.ptr[threadIdx.x];
        atomicOr(&cbm[c >> 5], 1u << (c & 31));
        if (blockIdx.x == 0)
            atomicOr(&p.markbm[c >> 5], 1u << (c & 31));
    }
    int gid = blockIdx.x * blockDim.x + threadIdx.x;
    int gst = gridDim.x * blockDim.x;
    uv4 z4 = {0u, 0u, 0u, 0u};
    for (int n = gid; n < N_NODES / 4; n += gst)
        cpstore4u(p.deg + (size_t)n * 4, z4);
    for (int n = gid; n < (CAPS * IN_CH) / 4; n += gst)
        cpstore4f(p.agg1 + (size_t)n * 4, (fv4){0.f, 0.f, 0.f, 0.f});
    for (int n = gid; n < (N_GRAPHS * OUT_CH) / 4; n += gst) {
        int c = (n * 4) & 127;
        cpstore4f(p.out + (size_t)n * 4,
                  (fv4){ p.b2[c], p.b2[c + 1], p.b2[c + 2], p.b2[c + 3] });
    }
    __syncthreads();
    int e0 = blockIdx.x * SCAN_CHUNK;
    for (int t = threadIdx.x; t < SCAN_V; t += blockDim.x) {
        int e = e0 + t * 4;
        if (e < N_EDGES) {
            iv4 d4 = *(const iv4*)(p.dst + e);
#pragma unroll
            for (int k = 0; k < 4; ++k) {
                int d = d4[k];
                if ((cbm[d >> 5] >> (d & 31)) & 1u) {
                    int s = p.src[e + k];
                    atomicOr(&p.markbm[s >> 5], 1u << (s & 31));
                    lbuf[atomicAdd(&scnt[0], 1)] = e + k;
                }
            }
        }
    }
    __syncthreads();
    if (threadIdx.x == 0) scnt[1] = atomicAdd(&p.cnt[2], scnt[0]);
    __syncthreads();
    for (int t = threadIdx.x; t < scnt[0]; t += blockDim.x) {
        int gi = scnt[1] + t;
        if (gi < CAP2) astore(&p.list2[gi], lbuf[t]);
    }
}

// Phase B: snapshot markbm; compact marked nodes -> slots (first 13 blocks);
// scan: marked-dst edges -> list1, srcs -> ndbm.
__device__ void ph_B(const P& p, int* smem) {
    unsigned* mbs = (unsigned*)smem;
    int* lbuf = smem + LBUF_OFF;
    int* scnt = smem + SCNT_OFF;
    if (threadIdx.x == 0) scnt[0] = 0;
    snap_bm(p.markbm, mbs);                 // ends with __syncthreads

    int gidx = blockIdx.x * blockDim.x + threadIdx.x;
    int lane = threadIdx.x & 63;
    if (blockIdx.x * (int)blockDim.x < BM_WORDS) {
        unsigned w = (gidx < BM_WORDS) ? mbs[gidx] : 0u;
        if (w) atomicOr(&p.ndbm[gidx], w);
        int c = __popc(w);
        int inc = c;
        for (int off = 1; off < 64; off <<= 1) {
            int t = __shfl_up(inc, off, 64);
            if (lane >= off) inc += t;
        }
        int total = __shfl(inc, 63, 64);
        if (total > 0) {
            int base = 0;
            if (lane == 63) base = atomicAdd(&p.cnt[0], total);
            base = __shfl(base, 63, 64);
            int slot = base + inc - c;
            unsigned ww = w;
            while (ww) {
                int b = __ffs(ww) - 1; ww &= ww - 1;
                int n = (gidx << 5) + b;
                if (slot < CAPS) { astore(&p.map1[n], slot); astore(&p.slotnode[slot], n); }
                else               astore(&p.map1[n], 0);
                ++slot;
            }
        }
    }

    int e0 = blockIdx.x * SCAN_CHUNK;
    for (int t = threadIdx.x; t < SCAN_V; t += blockDim.x) {
        int e = e0 + t * 4;
        if (e < N_EDGES) {
            iv4 d4 = *(const iv4*)(p.dst + e);
#pragma unroll
            for (int k = 0; k < 4; ++k) {
                int d = d4[k];
                if ((mbs[d >> 5] >> (d & 31)) & 1u) {
                    int s = p.src[e + k];
                    atomicOr(&p.ndbm[s >> 5], 1u << (s & 31));
                    lbuf[atomicAdd(&scnt[0], 1)] = e + k;
                }
            }
        }
    }
    __syncthreads();
    if (threadIdx.x == 0) scnt[1] = atomicAdd(&p.cnt[1], scnt[0]);
    __syncthreads();
    for (int t = threadIdx.x; t < scnt[0]; t += blockDim.x) {
        int gi = scnt[1] + t;
        if (gi < CAP1) astore(&p.list1[gi], lbuf[t]);
    }
}

// Phase C: snapshot ndbm; degree count only for dst in the needed set.
__device__ void ph_C(const P& p, int* smem) {
    unsigned* nds = (unsigned*)smem;
    snap_bm(p.ndbm, nds);                   // ends with __syncthreads
    int e0 = blockIdx.x * SCAN_CHUNK;
    for (int t = threadIdx.x; t < SCAN_V; t += blockDim.x) {
        int e = e0 + t * 4;
        if (e < N_EDGES) {
            iv4 d4 = *(const iv4*)(p.dst + e);
#pragma unroll
            for (int k = 0; k < 4; ++k) {
                int d = d4[k];
                if ((nds[d >> 5] >> (d & 31)) & 1u) atomicAdd(&p.deg[d], 1u);
            }
        }
    }
}

// Phase D: layer-1 aggregate: agg1[slot(dst)] += dis[src] * x[src].
// Wave = 4 edges x 16 channels.
__device__ void ph_D(const P& p) {
    int lane = threadIdx.x & 63;
    int g = lane >> 4;
    int c = lane & 15;
    int wid = blockIdx.x * (blockDim.x >> 6) + (threadIdx.x >> 6);
    int nw = gridDim.x * (blockDim.x >> 6);
    int n1 = min(aload(&p.cnt[1]), CAP1);
    for (int base = wid * 4; base < n1; base += nw * 4) {
        int myE = base + g;
        if (myE < n1) {
            int e = aload(&p.list1[myE]);
            int s = p.src[e];
            int d = p.dst[e];
            int slot = aload(&p.map1[d]); if (slot < 0) slot = 0;
            float w = rsqrtf((float)(1u + auload(&p.deg[s])));
            float xv = p.x[(size_t)s * IN_CH + c];
            atomicAdd(&p.agg1[(size_t)slot * IN_CH + c], w * xv);
        }
    }
}

// Phase E: layer-2. Recompute h1relu from agg1 in-register, W2 GEMV,
// atomics into out. Ballot row resolution; duplicates each accumulate.
__device__ void ph_E(const P& p, int* smem) {
    float* w1s = (float*)smem;              // 1024
    float* b1s = (float*)smem + 1024;       // 64
    float* w2s = (float*)smem + 1088;       // 8192
    int* cent  = smem + 9280;               // 128
    for (int t = threadIdx.x; t < IN_CH * HID_CH; t += blockDim.x) w1s[t] = p.W1[t];
    if (threadIdx.x < HID_CH) b1s[threadIdx.x] = p.b1[threadIdx.x];
    for (int t = threadIdx.x; t < HID_CH * OUT_CH; t += blockDim.x) w2s[t] = p.W2[t];
    if (threadIdx.x < 128) cent[threadIdx.x] = p.ptr[threadIdx.x];
    __syncthreads();
    int lane = threadIdx.x & 63;
    int c0 = cent[lane];
    int c1v = cent[lane + 64];
    int wid = blockIdx.x * (blockDim.x >> 6) + (threadIdx.x >> 6);
    int nw = gridDim.x * (blockDim.x >> 6);
    int n2 = min(aload(&p.cnt[2]), CAP2);
    for (int w = wid; w < n2 + N_GRAPHS; w += nw) {
        int s, d, selfrow = -1;
        if (w < n2) {
            int e = aload(&p.list2[w]);
            s = p.src[e]; d = p.dst[e];
        } else {
            selfrow = w - n2;
            s = cent[selfrow]; d = s;
        }
        int slot = aload(&p.map1[s]); if (slot < 0) slot = 0;
        float dis_s = rsqrtf((float)(1u + auload(&p.deg[s])));
        float dis_d = rsqrtf((float)(1u + auload(&p.deg[d])));
        float norm = dis_s * dis_d;
        float vc = 0.0f;
        if (lane < IN_CH)
            vc = dis_s * afload(&p.agg1[(size_t)slot * IN_CH + lane])
               + dis_s * dis_s * p.x[(size_t)s * IN_CH + lane];
        float h = b1s[lane];
#pragma unroll
        for (int c = 0; c < IN_CH; ++c)
            h += __shfl(vc, c, 64) * w1s[c * HID_CH + lane];
        h = fmaxf(h, 0.0f);
        float a0 = 0.0f, a1 = 0.0f;
#pragma unroll 8
        for (int j = 0; j < HID_CH; ++j) {
            float hv = __shfl(h, j, 64);
            a0 += hv * w2s[j * OUT_CH + lane];
            a1 += hv * w2s[j * OUT_CH + lane + 64];
        }
        a0 *= norm; a1 *= norm;
        if (selfrow >= 0) {
            atomicAdd(&p.out[selfrow * OUT_CH + lane], a0);
            atomicAdd(&p.out[selfrow * OUT_CH + lane + 64], a1);
        } else {
            unsigned long long b0 = __ballot(c0 == d);
            unsigned long long b1 = __ballot(c1v == d);
            while (b0) {
                int r = __ffsll((long long)b0) - 1; b0 &= b0 - 1;
                atomicAdd(&p.out[r * OUT_CH + lane], a0);
                atomicAdd(&p.out[r * OUT_CH + lane + 64], a1);
            }
            while (b1) {
                int r = __ffsll((long long)b1) - 1 + 64; b1 &= b1 - 1;
                atomicAdd(&p.out[r * OUT_CH + lane], a0);
                atomicAdd(&p.out[r * OUT_CH + lane + 64], a1);
            }
        }
    }
}

// ---------------- kernels ----------------

// Prep: zero markbm/ndbm (CP vec), barrier state, counters.
__global__ void k_prep(P p) {
    int i = blockIdx.x * blockDim.x + threadIdx.x;
    int st = gridDim.x * blockDim.x;
    uv4 z4 = {0u, 0u, 0u, 0u};
    for (int n = i; n < BM_PAD / 4; n += st) {
        cpstore4u(p.markbm + (size_t)n * 4, z4);
        cpstore4u(p.ndbm + (size_t)n * 4, z4);
    }
    for (int n = i; n < BAR_INTS; n += st) astore(((int*)p.bar) + n, 0);
    if (i < 16) astore(&p.cnt[i], 0);
}

// Cooperative mega-kernel: 5 phases, 4 relaxed tree barriers.
__global__ void __launch_bounds__(256) k_mega(P p) {
    __shared__ int smem[SMEM_INTS];
    ph_A(p, smem);  gbar(p.bar, 1);
    ph_B(p, smem);  gbar(p.bar, 2);
    ph_C(p, smem);  gbar(p.bar, 3);
    ph_D(p);        gbar(p.bar, 4);
    ph_E(p, smem);
}

// Standalone fallback kernels (dispatch boundaries = sync).
__global__ void __launch_bounds__(256) k_A(P p) { __shared__ int s[SMEM_INTS]; ph_A(p, s); }
__global__ void __launch_bounds__(256) k_B(P p) { __shared__ int s[SMEM_INTS]; ph_B(p, s); }
__global__ void __launch_bounds__(256) k_C(P p) { __shared__ int s[SMEM_INTS]; ph_C(p, s); }
__global__ void __launch_bounds__(256) k_D(P p) { ph_D(p); }
__global__ void __launch_bounds__(256) k_E(P p) { __shared__ int s[SMEM_INTS]; ph_E(p, s); }

// ---------------- launch ----------------

extern "C" void kernel_launch(void* const* d_in, const int* in_sizes, int n_in,
                              void* d_out, int out_size, void* d_ws, size_t ws_size,
                              hipStream_t stream) {
    P p;
    p.x   = (const float*)d_in[0];          // fp32 (validated)
    const int* edge = (const int*)d_in[1];  // int32 (validated)
    p.src = edge;
    p.dst = edge + N_EDGES;
    p.ptr = (const int*)d_in[2];
    p.W1  = (const float*)d_in[3];
    p.b1  = (const float*)d_in[4];
    p.W2  = (const float*)d_in[5];
    p.b2  = (const float*)d_in[6];
    p.out = (float*)d_out;

    char* q = (char*)d_ws;
    auto alloc = [&](size_t bytes) {
        char* r = q; q += (bytes + 255) & ~size_t(255); return r;
    };
    p.deg      = (unsigned*)alloc((size_t)N_NODES * 4);
    p.map1     = (int*)     alloc((size_t)N_NODES * 4);
    p.slotnode = (int*)     alloc((size_t)CAPS * 4);
    p.list1    = (int*)     alloc((size_t)CAP1 * 4);
    p.list2    = (int*)     alloc((size_t)CAP2 * 4);
    p.agg1     = (float*)   alloc((size_t)CAPS * IN_CH * 4);
    p.markbm   = (unsigned*)alloc((size_t)BM_PAD * 4);
    p.ndbm     = (unsigned*)alloc((size_t)BM_PAD * 4);
    p.cnt      = (int*)     alloc(256);
    p.bar      = (GBar*)    alloc(sizeof(GBar));

    hipLaunchKernelGGL(k_prep, dim3(8), dim3(256), 0, stream, p);

    void* args[] = { (void*)&p };
    hipError_t err = hipLaunchCooperativeKernel((const void*)k_mega,
                                                dim3(NBLK), dim3(256),
                                                args, 0, stream);
    if (err != hipSuccess) {
        (void)hipGetLastError();            // clear sticky error, use fallback
        hipLaunchKernelGGL(k_A, dim3(NBLK), dim3(256), 0, stream, p);
        hipLaunchKernelGGL(k_B, dim3(NBLK), dim3(256), 0, stream, p);
        hipLaunchKernelGGL(k_C, dim3(NBLK), dim3(256), 0, stream, p);
        hipLaunchKernelGGL(k_D, dim3(NBLK), dim3(256), 0, stream, p);
        hipLaunchKernelGGL(k_E, dim3(128),  dim3(256), 0, stream, p);
    }
}